// Round 10
// baseline (127.303 us; speedup 1.0000x reference)
//
#include <hip/hip_runtime.h>

// Flash attention fwd, B=2 S=8192 D=64. Round 10.
// = Round 7/9 structure (prep / attn split-K=4 / merge) plus:
//  1) cross-tile pipeline: QK^T(t+1) MFMA overlapped with softmax(t) VALU
//     (2-deep LDS staging, 2 barriers/tile, 2x-unrolled loop w/ named regs)
//  2) exp2 domain: Q scaled by 0.125/ln2, p = v_exp_f32(s-m) directly
//  3) defer-max: skip O/l rescale unless row max grew > 8 (log2 units)
// Fragment/softmax/exchange math verified rounds 4-9 (absmax 7.3e-4).

#define SEQ 8192
#define DH  64
#define QSCALE 0.1803368801111204f   // 0.125 / ln(2)

typedef __attribute__((ext_vector_type(8)))  short short8v;
typedef __attribute__((ext_vector_type(4)))  float f32x4;
typedef __attribute__((ext_vector_type(16))) float f32x16;

__device__ __forceinline__ uint f2bf(float f) {
    uint u = __float_as_uint(f);
    return (u + 0x7FFFu + ((u >> 16) & 1u)) >> 16;  // RNE
}
__device__ __forceinline__ float fexp2(float x) {
    float r; asm("v_exp_f32 %0, %1" : "=v"(r) : "v"(x)); return r;
}

// ws layout: Kb 2MB | Vt 2MB | Opart 16.78MB | Ml 0.5MB  = 21,495,808 B
#define WS_VT 2097152
#define WS_OP 4194304
#define WS_ML 20971520
#define WS_NEED 21495808ULL

// ============ prep: K convert + V transpose-convert ============
__global__ __launch_bounds__(256) void prep_k2(const float* __restrict__ K,
                                               const float* __restrict__ V,
                                               ushort* __restrict__ Kb,
                                               ushort* __restrict__ Vt) {
    const int bid = blockIdx.x, tid = threadIdx.x;
    if (bid < 256) {
        __shared__ ushort T[64][65];
        const int b = bid >> 7, s0 = (bid & 127) * 64;
        const float* base = V + ((size_t)b * SEQ + s0) * DH;
#pragma unroll
        for (int i = 0; i < 4; ++i) {
            int f4 = tid + 256 * i;
            int sl = f4 >> 4, d4 = (f4 & 15) * 4;
            float4 v = *(const float4*)(base + sl * DH + d4);
            T[d4 + 0][sl] = (ushort)f2bf(v.x);
            T[d4 + 1][sl] = (ushort)f2bf(v.y);
            T[d4 + 2][sl] = (ushort)f2bf(v.z);
            T[d4 + 3][sl] = (ushort)f2bf(v.w);
        }
        __syncthreads();
        ushort* outb = Vt + (size_t)b * DH * SEQ + s0;
#pragma unroll
        for (int i = 0; i < 8; ++i) {
            int u = tid + 256 * i;
            int d = u >> 5, s2 = (u & 31) * 2;
            uint pk = (uint)T[d][s2] | ((uint)T[d][s2 + 1] << 16);
            *(uint*)(outb + (size_t)d * SEQ + s2) = pk;
        }
    } else {
        size_t base = ((size_t)(bid - 256) * 256 + tid) * 16;
#pragma unroll
        for (int h = 0; h < 2; ++h) {
            float4 a = *(const float4*)(K + base + 8 * h);
            float4 c = *(const float4*)(K + base + 8 * h + 4);
            uint4 ko;
            ko.x = f2bf(a.x) | (f2bf(a.y) << 16);
            ko.y = f2bf(a.z) | (f2bf(a.w) << 16);
            ko.z = f2bf(c.x) | (f2bf(c.y) << 16);
            ko.w = f2bf(c.z) | (f2bf(c.w) << 16);
            *(uint4*)(Kb + base + 8 * h) = ko;
        }
    }
}

// ============ attn: 512 blocks x 256 threads, pipelined ============
__global__ __launch_bounds__(256, 2) void attn_k2(const float* __restrict__ Q,
                                                  const ushort* __restrict__ Kb,
                                                  const ushort* __restrict__ Vt,
                                                  float* __restrict__ Opart,
                                                  float* __restrict__ Ml) {
    __shared__ __align__(16) char smem[32768];  // 2 x (K 8KB + V 8KB)

    const int bid = blockIdx.x, tid = threadIdx.x;
    const int wk = (bid & 7) * 64 + (bid >> 3);       // XCD swizzle
    const int qt = wk & 63, quarter = (wk >> 6) & 3, b = wk >> 8;
    const int q0 = qt * 128, kq0 = quarter * 2048;
    const int lane = tid & 63, w = tid >> 6;
    const int q = lane & 31, hi = lane >> 5;

    // ---- Q fragments (0.125/ln2 folded -> exp2 domain) ----
    short8v qf[4];
    {
        const float* qr = Q + ((size_t)b * SEQ + q0 + 32 * w + q) * DH + 8 * hi;
#pragma unroll
        for (int t = 0; t < 4; ++t) {
            float4 a = *(const float4*)(qr + 16 * t);
            float4 c = *(const float4*)(qr + 16 * t + 4);
            union { uint u[4]; short8v v; } cv;
            cv.u[0] = f2bf(a.x * QSCALE) | (f2bf(a.y * QSCALE) << 16);
            cv.u[1] = f2bf(a.z * QSCALE) | (f2bf(a.w * QSCALE) << 16);
            cv.u[2] = f2bf(c.x * QSCALE) | (f2bf(c.y * QSCALE) << 16);
            cv.u[3] = f2bf(c.z * QSCALE) | (f2bf(c.w * QSCALE) << 16);
            qf[t] = cv.v;
        }
    }

    // ---- staging ----
    const int skey = tid >> 3, ocho = tid & 7;
    const ushort* Ks0 = Kb + ((size_t)b * SEQ + kq0 + skey) * DH + 8 * ocho;
    const ushort* Ks1 = Ks0 + (size_t)32 * DH;
    const ushort* Vs0 = Vt + ((size_t)b * DH + skey) * SEQ + kq0 + 8 * ocho;
    const ushort* Vs1 = Vs0 + (size_t)32 * SEQ;

    short8v kr0, kr1, vr0, vr1;
    auto stage_load = [&](int kt) {
        kr0 = *(const short8v*)(Ks0 + (size_t)kt * 64 * DH);
        kr1 = *(const short8v*)(Ks1 + (size_t)kt * 64 * DH);
        vr0 = *(const short8v*)(Vs0 + kt * 64);
        vr1 = *(const short8v*)(Vs1 + kt * 64);
    };
    const uint kslot = (uint)((ocho ^ (skey & 7)) << 4);
    auto stage_write = [&](char* buf) {
        char* vbp = buf + 8192;
        *(short8v*)(buf + skey * 128 + kslot) = kr0;
        *(short8v*)(buf + (skey + 32) * 128 + kslot) = kr1;
        *(short8v*)(vbp + skey * 128 + kslot) = vr0;
        *(short8v*)(vbp + (skey + 32) * 128 + kslot) = vr1;
    };

    f32x16 o0, o1;
#pragma unroll
    for (int j = 0; j < 16; ++j) { o0[j] = 0.f; o1[j] = 0.f; }
    float m = -1e30f, l = 0.f;

    auto qkt = [&](char* buf, f32x16& d0, f32x16& d1) {
        short8v ka[8];
#pragma unroll
        for (int kb2 = 0; kb2 < 2; ++kb2)
#pragma unroll
            for (int t = 0; t < 4; ++t) {
                int row = kb2 * 32 + q;
                ka[kb2 * 4 + t] = *(const short8v*)(buf + row * 128 + (((2 * t + hi) ^ (row & 7)) << 4));
            }
#pragma unroll
        for (int j = 0; j < 16; ++j) { d0[j] = 0.f; d1[j] = 0.f; }
        __builtin_amdgcn_s_setprio(1);
#pragma unroll
        for (int t = 0; t < 4; ++t) {
            d0 = __builtin_amdgcn_mfma_f32_32x32x16_bf16(ka[t],     qf[t], d0, 0, 0, 0);
            d1 = __builtin_amdgcn_mfma_f32_32x32x16_bf16(ka[4 + t], qf[t], d1, 0, 0, 0);
        }
        __builtin_amdgcn_s_setprio(0);
    };

    // ---- prologue: tiles 0,1 staged; scores(0) computed ----
    stage_load(0); stage_write(smem); __syncthreads();
    stage_load(1);
    f32x16 sA0, sA1, sB0, sB1;
    qkt(smem, sA0, sA1);
    stage_write(smem + 16384); __syncthreads();
    stage_load(2);

    // ---- iteration body: softmax/PV(t) overlapped with QK^T(t+1) ----
    auto tile_body = [&](int t, f32x16& c0, f32x16& c1, f32x16& n0, f32x16& n1) {
        char* curb = smem + (t & 1) * 16384;
        char* nxtb = smem + ((t + 1) & 1) * 16384;
        // V-frags(t)
        short8v va[8];
#pragma unroll
        for (int db = 0; db < 2; ++db)
#pragma unroll
            for (int kc = 0; kc < 4; ++kc) {
                int row = db * 32 + q;
                va[db * 4 + kc] = *(const short8v*)(curb + 8192 + row * 128 + (((2 * kc + hi) ^ (row & 7)) << 4));
            }
        __syncthreads();  // barrier 1: all reads of curb done -> safe to overwrite

        // QK^T(t+1) [MFMA] -- independent of softmax below, co-scheduled
        if (t + 1 < 32) qkt(nxtb, n0, n1);

        // ---- online softmax on scores(t) (exp2 domain, defer-max) ----
        float tm;
        {
            f32x16 tv;
#pragma unroll
            for (int j = 0; j < 16; ++j) tv[j] = fmaxf(c0[j], c1[j]);
#pragma unroll
            for (int j = 0; j < 8; ++j) tv[j] = fmaxf(tv[j], tv[j + 8]);
#pragma unroll
            for (int j = 0; j < 4; ++j) tv[j] = fmaxf(tv[j], tv[j + 4]);
            tm = fmaxf(fmaxf(tv[0], tv[1]), fmaxf(tv[2], tv[3]));
        }
        tm = fmaxf(tm, __shfl_xor(tm, 32));
        float mnew = fmaxf(m, tm);
        if (!__all(mnew <= m + 8.0f)) {       // defer-max: rescale only on big growth
            float sc = fexp2(m - mnew);
            l *= sc;
#pragma unroll
            for (int j = 0; j < 16; ++j) { o0[j] *= sc; o1[j] *= sc; }
            m = mnew;
        }
#pragma unroll
        for (int j = 0; j < 16; ++j) {
            c0[j] = fexp2(c0[j] - m);
            c1[j] = fexp2(c1[j] - m);
        }
        {
            f32x16 pa;
#pragma unroll
            for (int j = 0; j < 16; ++j) pa[j] = c0[j] + c1[j];
#pragma unroll
            for (int j = 0; j < 8; ++j) pa[j] += pa[j + 8];
#pragma unroll
            for (int j = 0; j < 4; ++j) pa[j] += pa[j + 4];
            float ls = (pa[0] + pa[1]) + (pa[2] + pa[3]);
            ls += __shfl_xor(ls, 32);
            l += ls;
        }

        // ---- pack P -> bf16 + cross-half exchange -> B-frags ----
        short8v bfrag[4];
        {
            uint W[16];
#pragma unroll
            for (int i = 0; i < 8; ++i) {
#pragma unroll
                for (int c = 0; c < 2; ++c) {
                    int kb3 = i >> 2, rg = ((i & 3) << 2) | (c << 1);
                    float lo = kb3 ? c1[rg] : c0[rg];
                    float hh = kb3 ? c1[rg + 1] : c0[rg + 1];
                    uint ww;
                    asm("v_cvt_pk_bf16_f32 %0, %1, %2" : "=v"(ww) : "v"(lo), "v"(hh));
                    W[2 * i + c] = ww;
                }
            }
#pragma unroll
            for (int kc = 0; kc < 4; ++kc) {
                uint w0 = W[4 * kc], w1 = W[4 * kc + 1], w2 = W[4 * kc + 2], w3 = W[4 * kc + 3];
                uint y02 = hi ? w0 : w2;
                uint z02 = __shfl_xor(y02, 32);
                uint y13 = hi ? w1 : w3;
                uint z13 = __shfl_xor(y13, 32);
                union { uint u[4]; short8v v; } cv;
                cv.u[0] = hi ? z02 : w0;
                cv.u[1] = hi ? z13 : w1;
                cv.u[2] = hi ? w2 : z02;
                cv.u[3] = hi ? w3 : z13;
                bfrag[kc] = cv.v;
            }
        }

        // ---- O^T += V^T P^T ----
        __builtin_amdgcn_s_setprio(1);
#pragma unroll
        for (int kc = 0; kc < 4; ++kc) {
            o0 = __builtin_amdgcn_mfma_f32_32x32x16_bf16(va[kc],     bfrag[kc], o0, 0, 0, 0);
            o1 = __builtin_amdgcn_mfma_f32_32x32x16_bf16(va[4 + kc], bfrag[kc], o1, 0, 0, 0);
        }
        __builtin_amdgcn_s_setprio(0);

        // ---- stage tile t+2 into curb; issue load t+3 ----
        if (t + 2 < 32) {
            stage_write(curb);
            if (t + 3 < 32) stage_load(t + 3);
        }
        __syncthreads();  // barrier 2: curb now holds tile t+2
    };

#pragma unroll 1
    for (int t = 0; t < 32; t += 2) {
        tile_body(t,     sA0, sA1, sB0, sB1);
        tile_body(t + 1, sB0, sB1, sA0, sA1);
    }

    // ---- epilogue: partial stores in C-fragment layout ----
    float* Op = Opart + ((((size_t)quarter * 2 + b) * 64 + qt) * 4 + w) * 2048;
#pragma unroll
    for (int j = 0; j < 4; ++j) {
        f32x4 t0 = { o0[4 * j], o0[4 * j + 1], o0[4 * j + 2], o0[4 * j + 3] };
        *(f32x4*)(Op + j * 256 + lane * 4) = t0;
        f32x4 t1 = { o1[4 * j], o1[4 * j + 1], o1[4 * j + 2], o1[4 * j + 3] };
        *(f32x4*)(Op + (4 + j) * 256 + lane * 4) = t1;
    }
    if (hi == 0) {
        float2 v2 = make_float2(m, l);
        *(float2*)(Ml + ((size_t)quarter * 16384 + (size_t)b * 8192 + q0 + 32 * w + q) * 2) = v2;
    }
}

// ============ merge: 4 partials (exp2 domain weights) ============
__global__ __launch_bounds__(256) void merge_k2(const float* __restrict__ Opart,
                                                const float* __restrict__ Ml,
                                                float* __restrict__ O) {
    int g = blockIdx.x * 256 + threadIdx.x;
    int r = g >> 3, d0 = (g & 7) * 8;
    int bb = r >> 13, row = r & 8191;
    int qt = row >> 7, w = (row >> 5) & 3, q = row & 31;
    float mi[4], li[4];
#pragma unroll
    for (int i = 0; i < 4; ++i) {
        float2 v2 = *(const float2*)(Ml + ((size_t)i * 16384 + r) * 2);
        mi[i] = v2.x; li[i] = v2.y;
    }
    float M = fmaxf(fmaxf(mi[0], mi[1]), fmaxf(mi[2], mi[3]));
    float e4[4]; float lsum = 0.f;
#pragma unroll
    for (int i = 0; i < 4; ++i) { e4[i] = fexp2(mi[i] - M); lsum += e4[i] * li[i]; }
    float inv = 1.0f / lsum;
    float aAx = 0, aAy = 0, aAz = 0, aAw = 0, aBx = 0, aBy = 0, aBz = 0, aBw = 0;
    const int oh = (d0 >= 32) ? 4 : 0;
    const int s8 = (d0 & 31) >> 3;
#pragma unroll
    for (int i = 0; i < 4; ++i) {
        size_t wb = ((((size_t)i * 2 + bb) * 64 + qt) * 4 + w) * 2048;
        const float* pa = Opart + wb + (size_t)(oh + s8) * 256 + q * 4;
        const float* pb = Opart + wb + (size_t)(oh + s8) * 256 + (q + 32) * 4;
        float4 va4 = *(const float4*)pa;
        float4 vb4 = *(const float4*)pb;
        aAx += e4[i] * va4.x; aAy += e4[i] * va4.y; aAz += e4[i] * va4.z; aAw += e4[i] * va4.w;
        aBx += e4[i] * vb4.x; aBy += e4[i] * vb4.y; aBz += e4[i] * vb4.z; aBw += e4[i] * vb4.w;
    }
    float* op = O + (size_t)r * DH + d0;
    float4 r0 = { aAx * inv, aAy * inv, aAz * inv, aAw * inv };
    float4 r1 = { aBx * inv, aBy * inv, aBz * inv, aBw * inv };
    *(float4*)op = r0;
    *(float4*)(op + 4) = r1;
}

// ================= round-3 fallback (no ws) =================
#define BQ  64
#define BK  64
#define NT  (SEQ / 2 / BK)
#define OFF_K 0
#define OFF_V 16384
#define OFF_P 32768
#define LDS_BYTES 49152

__device__ __forceinline__ ushort f2bfs(float f) {
    uint u = __float_as_uint(f);
    return (ushort)((u + 0x7FFFu + ((u >> 16) & 1u)) >> 16);
}
__device__ __forceinline__ uint swz(uint row, uint colByte) {
    return row * 128u + (colByte ^ ((row & 7u) << 4));
}

__global__ __launch_bounds__(512, 2) void attn_fwd_mfma(
    const float* __restrict__ Q, const float* __restrict__ K,
    const float* __restrict__ V, float* __restrict__ O)
{
    __shared__ ulong2 smem_[LDS_BYTES / 16];
    char* smem = (char*)smem_;
    const int tid = threadIdx.x;
    const int lane = tid & 63;
    const int wid = tid >> 6;
    const int grp = wid >> 2;
    const int w = wid & 3;
    const int l15 = lane & 15;
    const int l4 = lane >> 4;
    const int batch = blockIdx.y;
    const int q0 = blockIdx.x * BQ;
    const int m0 = w * 16;
    const float* Qb = Q + ((size_t)batch * SEQ + q0) * DH;
    const float* Kb = K + ((size_t)batch * SEQ + (size_t)grp * (SEQ / 2)) * DH;
    const float* Vb = V + ((size_t)batch * SEQ + (size_t)grp * (SEQ / 2)) * DH;
    short8v qf[2];
    {
        const float* qr = Qb + (m0 + l15) * DH;
#pragma unroll
        for (int t = 0; t < 2; ++t) {
            float4 a = *(const float4*)(qr + t * 32 + l4 * 8);
            float4 bb = *(const float4*)(qr + t * 32 + l4 * 8 + 4);
            short8v v;
            v[0] = (short)f2bfs(a.x * 0.125f); v[1] = (short)f2bfs(a.y * 0.125f);
            v[2] = (short)f2bfs(a.z * 0.125f); v[3] = (short)f2bfs(a.w * 0.125f);
            v[4] = (short)f2bfs(bb.x * 0.125f); v[5] = (short)f2bfs(bb.y * 0.125f);
            v[6] = (short)f2bfs(bb.z * 0.125f); v[7] = (short)f2bfs(bb.w * 0.125f);
            qf[t] = v;
        }
    }
    const int tg = tid & 255;
    const int k2 = tg & 31;
    const int dq0 = tg >> 5;
    char* kb = smem + OFF_K + grp * 8192;
    char* vb = smem + OFF_V + grp * 8192;
    char* pb = smem + OFF_P + wid * 2048;
    float4 kp[4], vp[4];
    auto issue = [&](int kt) {
        const float* Kt = Kb + (size_t)kt * BK * DH;
        const float* Vtp = Vb + (size_t)kt * BK * DH;
#pragma unroll
        for (int i = 0; i < 4; ++i) kp[i] = ((const float4*)Kt)[tg + 256 * i];
#pragma unroll
        for (int dd = 0; dd < 2; ++dd) {
            int dq = dq0 + 8 * dd;
            vp[2 * dd] = *(const float4*)(Vtp + (2 * k2) * DH + 4 * dq);
            vp[2 * dd + 1] = *(const float4*)(Vtp + (2 * k2 + 1) * DH + 4 * dq);
        }
    };
    auto stash = [&]() {
#pragma unroll
        for (int i = 0; i < 4; ++i) {
            int f = tg + 256 * i;
            uint row = (uint)(f >> 4), c4 = (uint)(f & 15);
            uint2 h;
            h.x = (uint)f2bfs(kp[i].x) | ((uint)f2bfs(kp[i].y) << 16);
            h.y = (uint)f2bfs(kp[i].z) | ((uint)f2bfs(kp[i].w) << 16);
            *(uint2*)(kb + swz(row, c4 * 8)) = h;
        }
#pragma unroll
        for (int dd = 0; dd < 2; ++dd) {
            int dq = dq0 + 8 * dd;
            float a0[4] = {vp[2*dd].x, vp[2*dd].y, vp[2*dd].z, vp[2*dd].w};
            float a1[4] = {vp[2*dd+1].x, vp[2*dd+1].y, vp[2*dd+1].z, vp[2*dd+1].w};
#pragma unroll
            for (int e = 0; e < 4; ++e) {
                uint pk = (uint)f2bfs(a0[e]) | ((uint)f2bfs(a1[e]) << 16);
                *(uint*)(vb + swz((uint)(4 * dq + e), (uint)(4 * k2))) = pk;
            }
        }
    };
    f32x4 o[4];
#pragma unroll
    for (int j = 0; j < 4; ++j) o[j] = (f32x4){0.f, 0.f, 0.f, 0.f};
    float mrow[4] = {-1e30f, -1e30f, -1e30f, -1e30f};
    float lrow[4] = {0.f, 0.f, 0.f, 0.f};
    issue(0);
    stash();
    __syncthreads();
    for (int kt = 0; kt < NT; ++kt) {
        if (kt + 1 < NT) issue(kt + 1);
        f32x4 s[4];
#pragma unroll
        for (int j = 0; j < 4; ++j) s[j] = (f32x4){0.f, 0.f, 0.f, 0.f};
#pragma unroll
        for (int t = 0; t < 2; ++t) {
#pragma unroll
            for (int j = 0; j < 4; ++j) {
                short8v kf = *(const short8v*)(kb + swz((uint)(j * 16 + l15),
                                                        (uint)(t * 64 + l4 * 16)));
                s[j] = __builtin_amdgcn_mfma_f32_16x16x32_bf16(qf[t], kf, s[j], 0, 0, 0);
            }
        }
#pragma unroll
        for (int r = 0; r < 4; ++r) {
            float tm = fmaxf(fmaxf(s[0][r], s[1][r]), fmaxf(s[2][r], s[3][r]));
            tm = fmaxf(tm, __shfl_xor(tm, 1));
            tm = fmaxf(tm, __shfl_xor(tm, 2));
            tm = fmaxf(tm, __shfl_xor(tm, 4));
            tm = fmaxf(tm, __shfl_xor(tm, 8));
            float mn = fmaxf(mrow[r], tm);
            float sc = __expf(mrow[r] - mn);
            mrow[r] = mn;
            float p0 = __expf(s[0][r] - mn);
            float p1 = __expf(s[1][r] - mn);
            float p2 = __expf(s[2][r] - mn);
            float p3 = __expf(s[3][r] - mn);
            float ls = (p0 + p1) + (p2 + p3);
            ls += __shfl_xor(ls, 1);
            ls += __shfl_xor(ls, 2);
            ls += __shfl_xor(ls, 4);
            ls += __shfl_xor(ls, 8);
            lrow[r] = lrow[r] * sc + ls;
            o[0][r] *= sc; o[1][r] *= sc; o[2][r] *= sc; o[3][r] *= sc;
            uint rowb = (uint)(l4 * 4 + r);
            *(ushort*)(pb + swz(rowb, (uint)((0 * 16 + l15) * 2))) = f2bfs(p0);
            *(ushort*)(pb + swz(rowb, (uint)((1 * 16 + l15) * 2))) = f2bfs(p1);
            *(ushort*)(pb + swz(rowb, (uint)((2 * 16 + l15) * 2))) = f2bfs(p2);
            *(ushort*)(pb + swz(rowb, (uint)((3 * 16 + l15) * 2))) = f2bfs(p3);
        }
        short8v pf[2];
#pragma unroll
        for (int t = 0; t < 2; ++t)
            pf[t] = *(const short8v*)(pb + swz((uint)l15, (uint)(t * 64 + l4 * 16)));
#pragma unroll
        for (int t = 0; t < 2; ++t) {
#pragma unroll
            for (int j = 0; j < 4; ++j) {
                short8v vf = *(const short8v*)(vb + swz((uint)(j * 16 + l15),
                                                        (uint)(t * 64 + l4 * 16)));
                o[j] = __builtin_amdgcn_mfma_f32_16x16x32_bf16(pf[t], vf, o[j], 0, 0, 0);
            }
        }
        __syncthreads();
        if (kt + 1 < NT) stash();
        __syncthreads();
    }
    float* A0 = (float*)smem;
    float* M0 = (float*)(smem + 20480);
    float* L0 = (float*)(smem + 20736);
    if (grp == 0) {
#pragma unroll
        for (int r = 0; r < 4; ++r) {
            uint rowA = (uint)(m0 + l4 * 4 + r);
#pragma unroll
            for (int j = 0; j < 4; ++j)
                A0[rowA * 68 + j * 16 + l15] = o[j][r];
            if (l15 == 0) { M0[rowA] = mrow[r]; L0[rowA] = lrow[r]; }
        }
    }
    __syncthreads();
    if (grp == 1) {
        float* Ob = O + ((size_t)batch * SEQ + q0) * DH;
#pragma unroll
        for (int r = 0; r < 4; ++r) {
            uint rowA = (uint)(m0 + l4 * 4 + r);
            float m1 = mrow[r], l1 = lrow[r];
            float m0r = M0[rowA], l0r = L0[rowA];
            float mn = fmaxf(m0r, m1);
            float s0 = __expf(m0r - mn), s1 = __expf(m1 - mn);
            float inv = 1.0f / (l0r * s0 + l1 * s1);
#pragma unroll
            for (int j = 0; j < 4; ++j) {
                float af = A0[rowA * 68 + j * 16 + l15] * s0 + o[j][r] * s1;
                Ob[rowA * DH + j * 16 + l15] = af * inv;
            }
        }
    }
}

// ============ launcher ============
extern "C" void kernel_launch(void* const* d_in, const int* in_sizes, int n_in,
                              void* d_out, int out_size, void* d_ws, size_t ws_size,
                              hipStream_t stream) {
    (void)n_in; (void)out_size;
    const float* x1 = (const float*)d_in[0];
    const float* x2 = (const float*)d_in[1];
    const float* x3 = (const float*)d_in[2];
    float* out = (float*)d_out;
    const int B = in_sizes[0] / (SEQ * DH);

    if (B == 2 && ws_size >= WS_NEED) {
        ushort* Kb = (ushort*)d_ws;
        ushort* Vt = (ushort*)((char*)d_ws + WS_VT);
        float* Opart = (float*)((char*)d_ws + WS_OP);
        float* Mlp = (float*)((char*)d_ws + WS_ML);
        prep_k2<<<512, 256, 0, stream>>>(x2, x3, Kb, Vt);
        attn_k2<<<512, 256, 0, stream>>>(x1, Kb, Vt, Opart, Mlp);
        merge_k2<<<512, 256, 0, stream>>>(Opart, Mlp, out);
    } else {
        attn_fwd_mfma<<<dim3(SEQ / BQ, B), 512, 0, stream>>>(x1, x2, x3, out);
    }
}